// Round 2
// baseline (47.495 us; speedup 1.0000x reference)
//
#include <hip/hip_runtime.h>
#include <cstdint>

typedef unsigned long long u64;
typedef unsigned int u32;

#define BB 64
#define DD 128
#define OO 512
#define II 512
#define OT 64   // o-tile per block

// ---------------------------------------------------------------------------
// Input-format detection (device side, per block; uniform branch afterwards).
// mode 0: raw bytes {0,1} (numpy bool / int8)
// mode 1: int32 {0,1}
// mode 2: float32 {0.0f, 1.0f}
// Reads 32 u32 words of the weight buffer. For random 0/1 bytes the chance
// that all 32 words are <=1 is 8^-32; that they all match {0,0x3F800000} is
// ~16^-32. Deterministic across calls (same input buffer).
// ---------------------------------------------------------------------------
__device__ __forceinline__ int detect_mode(const u32* __restrict__ w) {
    bool all01 = true, allf = true;
#pragma unroll
    for (int i = 0; i < 32; ++i) {
        u32 v = w[i];
        all01 = all01 && (v <= 1u);
        allf  = allf  && (v == 0u || v == 0x3F800000u);
    }
    return all01 ? 1 : (allf ? 2 : 0);
}

// Pack 64 consecutive elements (starting at element index elem_off) into a
// 64-bit mask. Element size depends on mode. Bit order is identical for x and
// w, so popcount(xor) is invariant to it.
__device__ __forceinline__ u64 pack64(const void* __restrict__ base, int mode,
                                      size_t elem_off) {
    u64 r = 0;
    if (mode == 0) {
        // bytes {0,1}: 4 bytes -> 4 bits via multiply trick (no carry
        // collisions: contributions land on distinct bits 24..27).
        const uint4* s = (const uint4*)((const uint8_t*)base + elem_off);
#pragma unroll
        for (int j = 0; j < 4; ++j) {
            uint4 v = s[j];
            u32 n0 = ((v.x * 0x01020408u) >> 24) & 0xFu;
            u32 n1 = ((v.y * 0x01020408u) >> 24) & 0xFu;
            u32 n2 = ((v.z * 0x01020408u) >> 24) & 0xFu;
            u32 n3 = ((v.w * 0x01020408u) >> 24) & 0xFu;
            u32 bits16 = n0 | (n1 << 4) | (n2 << 8) | (n3 << 12);
            r |= (u64)bits16 << (16 * j);
        }
    } else if (mode == 1) {
        const uint4* s = (const uint4*)((const u32*)base + elem_off);
#pragma unroll
        for (int j = 0; j < 16; ++j) {
            uint4 v = s[j];
            u32 bits = (v.x & 1u) | ((v.y & 1u) << 1) |
                       ((v.z & 1u) << 2) | ((v.w & 1u) << 3);
            r |= (u64)bits << (4 * j);
        }
    } else {
        // float 0.0/1.0: bit23 of 0x3F800000 is 1, of 0x0 is 0.
        const uint4* s = (const uint4*)((const u32*)base + elem_off);
#pragma unroll
        for (int j = 0; j < 16; ++j) {
            uint4 v = s[j];
            u32 bits = ((v.x >> 23) & 1u) | (((v.y >> 23) & 1u) << 1) |
                       (((v.z >> 23) & 1u) << 2) | (((v.w >> 23) & 1u) << 3);
            r |= (u64)bits << (4 * j);
        }
    }
    return r;
}

// One block: fixed d, 64-wide o-tile, all 64 b's.
// Phase A: pack x[0:64, d, :] -> xp LDS (64 rows x 8 u64).
// Phase B: pack w[d, o0:o0+64, :] -> wp LDS (64 rows x 8 u64, padded).
// Phase C: thread owns o = tid&63, b-range = (tid>>6)*16 .. +15.
//          matches = 512 - popcount(x ^ w); out = (matches > bias) as int32.
__global__ __launch_bounds__(256)
void binlin_kernel(const void* __restrict__ x, const void* __restrict__ w,
                   const float* __restrict__ bias, int* __restrict__ out) {
    __shared__ u64 xp[BB][8];
    __shared__ u64 wp[OT][9];   // pad row to 9 u64: one-time wp read 4-way max

    const int tid = threadIdx.x;
    const int blk = blockIdx.x;
    const int d   = blk >> 3;           // OO/OT == 8 tiles per d
    const int o0  = (blk & 7) * OT;

    const int mode = detect_mode((const u32*)w);

    // Phase A: 512 packed words / 256 threads = 2 each
#pragma unroll
    for (int t = tid; t < BB * 8; t += 256) {
        int b = t >> 3, k = t & 7;
        xp[b][k] = pack64(x, mode, ((size_t)b * DD + d) * II + (size_t)k * 64);
    }
    // Phase B
#pragma unroll
    for (int t = tid; t < OT * 8; t += 256) {
        int o = t >> 3, k = t & 7;
        wp[o][k] = pack64(w, mode, ((size_t)d * OO + o0 + o) * II + (size_t)k * 64);
    }
    __syncthreads();

    const int o  = tid & 63;
    const int b0 = (tid >> 6) * 16;

    u64 wr[8];
#pragma unroll
    for (int k = 0; k < 8; ++k) wr[k] = wp[o][k];
    const float bv = bias[d * OO + o0 + o];

    int* outp = out + (size_t)d * OO + o0 + o;
#pragma unroll 4
    for (int bi = 0; bi < 16; ++bi) {
        const int b = b0 + bi;
        int m = 0;
#pragma unroll
        for (int k = 0; k < 8; ++k) m += __popcll(xp[b][k] ^ wr[k]);
        const float act = (float)(512 - m);   // exact integer in fp32
        outp[(size_t)b * (DD * OO)] = (act > bv) ? 1 : 0;
    }
}

extern "C" void kernel_launch(void* const* d_in, const int* in_sizes, int n_in,
                              void* d_out, int out_size, void* d_ws, size_t ws_size,
                              hipStream_t stream) {
    const void*  x    = d_in[0];                 // (B, D, I) binary
    const void*  w    = d_in[1];                 // (D, O, I) binary
    const float* bias = (const float*)d_in[2];   // (D, O) f32
    int*         out  = (int*)d_out;             // (B, D, O) bool as int32

    binlin_kernel<<<DD * (OO / OT), 256, 0, stream>>>(x, w, bias, out);
}